// Round 2
// baseline (1106.034 us; speedup 1.0000x reference)
//
#include <hip/hip_runtime.h>

#define NUU 8039
#define NII 32770
#define NBB 4771
#define NTOT (NUU + NII + NBB)   // 45580
#define EMB 32
#define NNZ_E 2000000
#define EPSF 1e-8f
#define L2F 1e-5f
#define NBATCH 2048
#define KB 100
#define SCAN_T 1024
#define CHUNK ((NTOT + SCAN_T - 1) / SCAN_T)   // 45

__device__ __forceinline__ float get_x(const float* __restrict__ ufeat,
                                       const float* __restrict__ ifeat,
                                       const float* __restrict__ bfeat,
                                       int i, int d) {
    if (i < NUU) return ufeat[i * EMB + d];
    if (i < NUU + NII) return ifeat[(i - NUU) * EMB + d];
    return bfeat[(i - NUU - NII) * EMB + d];
}

// Degree counting with int atomics (exact).
__global__ void k_deg(const int* __restrict__ rows, const int* __restrict__ cols,
                      int* __restrict__ dv, int* __restrict__ de) {
    int e = blockIdx.x * blockDim.x + threadIdx.x;
    if (e < NNZ_E) {
        atomicAdd(&dv[rows[e]], 1);
        atomicAdd(&de[cols[e]], 1);
    }
}

// Single-block exclusive scan over both degree arrays -> CSR offsets + cursor
// copies + inverse-sqrt degree scalings.
__global__ void k_scan(const int* __restrict__ dv, const int* __restrict__ de,
                       int* __restrict__ off_r, int* __restrict__ cur_r,
                       int* __restrict__ off_c, int* __restrict__ cur_c,
                       float* __restrict__ dvi, float* __restrict__ dei) {
    __shared__ int part[SCAN_T];
    int t = threadIdx.x;
    int base = t * CHUNK;

    // ---- pass 1: rows (dv) ----
    int s = 0;
    for (int i = 0; i < CHUNK; ++i) {
        int idx = base + i;
        if (idx < NTOT) s += dv[idx];
    }
    part[t] = s;
    __syncthreads();
    for (int off = 1; off < SCAN_T; off <<= 1) {
        int v = part[t];
        if (t >= off) v += part[t - off];
        __syncthreads();
        part[t] = v;
        __syncthreads();
    }
    int run = (t > 0) ? part[t - 1] : 0;
    for (int i = 0; i < CHUNK; ++i) {
        int idx = base + i;
        if (idx < NTOT) {
            off_r[idx] = run;
            cur_r[idx] = run;
            int c = dv[idx];
            dvi[idx] = 1.0f / (sqrtf((float)c) + EPSF);
            run += c;
        }
    }
    __syncthreads();

    // ---- pass 2: cols (de) ----
    s = 0;
    for (int i = 0; i < CHUNK; ++i) {
        int idx = base + i;
        if (idx < NTOT) s += de[idx];
    }
    part[t] = s;
    __syncthreads();
    for (int off = 1; off < SCAN_T; off <<= 1) {
        int v = part[t];
        if (t >= off) v += part[t - off];
        __syncthreads();
        part[t] = v;
        __syncthreads();
    }
    run = (t > 0) ? part[t - 1] : 0;
    for (int i = 0; i < CHUNK; ++i) {
        int idx = base + i;
        if (idx < NTOT) {
            off_c[idx] = run;
            cur_c[idx] = run;
            int c = de[idx];
            dei[idx] = 1.0f / (sqrtf((float)c) + EPSF);
            run += c;
        }
    }
}

// Fill both adjacency lists: adj_c[c-bucket] = r, adj_r[r-bucket] = c.
__global__ void k_fill(const int* __restrict__ rows, const int* __restrict__ cols,
                       int* __restrict__ cur_r, int* __restrict__ cur_c,
                       int* __restrict__ adj_r, int* __restrict__ adj_c) {
    int e = blockIdx.x * blockDim.x + threadIdx.x;
    if (e < NNZ_E) {
        int r = rows[e], c = cols[e];
        adj_r[atomicAdd(&cur_r[r], 1)] = c;
        adj_c[atomicAdd(&cur_c[c], 1)] = r;
    }
}

// u[c][d] = dei[c] * sum_{r in adj_c[c]} x[r][d] * dvi[r]
// One 64-lane wave per node: lanes (d = lane&31), two halves split the list.
__global__ void k_g1(const int* __restrict__ off_c, const int* __restrict__ de,
                     const int* __restrict__ adj_c,
                     const float* __restrict__ ufeat, const float* __restrict__ ifeat,
                     const float* __restrict__ bfeat,
                     const float* __restrict__ dvi, const float* __restrict__ dei,
                     float* __restrict__ u) {
    int wid = (blockIdx.x * blockDim.x + threadIdx.x) >> 6;
    if (wid >= NTOT) return;
    int lane = threadIdx.x & 63;
    int d = lane & 31, half = lane >> 5;
    int s = off_c[wid], n = de[wid];
    float acc = 0.0f;
    for (int k = s + half; k < s + n; k += 2) {
        int r = adj_c[k];
        acc += get_x(ufeat, ifeat, bfeat, r, d) * dvi[r];
    }
    acc += __shfl_xor(acc, 32, 64);
    if (half == 0) u[wid * EMB + d] = acc * dei[wid];
}

// emb[r][d] = x[r][d]/2 + dvi[r]/3 * sum_{c in adj_r[r]} u[c][d]; fused loss.
__global__ void k_g2(const int* __restrict__ off_r, const int* __restrict__ dv,
                     const int* __restrict__ adj_r,
                     const float* __restrict__ ufeat, const float* __restrict__ ifeat,
                     const float* __restrict__ bfeat,
                     const float* __restrict__ dvi, const float* __restrict__ u,
                     float* __restrict__ emb, float* __restrict__ lacc) {
    int wid = (blockIdx.x * blockDim.x + threadIdx.x) >> 6;
    int lane = threadIdx.x & 63;
    float sq = 0.0f;
    if (wid < NTOT) {
        int d = lane & 31, half = lane >> 5;
        int s = off_r[wid], n = dv[wid];
        float acc = 0.0f;
        for (int k = s + half; k < s + n; k += 2) {
            int c = adj_r[k];
            acc += u[c * EMB + d];
        }
        acc += __shfl_xor(acc, 32, 64);
        if (half == 0) {
            float e = 0.5f * get_x(ufeat, ifeat, bfeat, wid, d)
                    + (dvi[wid] * (1.0f / 3.0f)) * acc;
            emb[wid * EMB + d] = e;
            sq = e * e;
        }
    }
#pragma unroll
    for (int off = 32; off > 0; off >>= 1) sq += __shfl_down(sq, off, 64);
    __shared__ float smem[4];
    int w = threadIdx.x >> 6;
    if ((threadIdx.x & 63) == 0) smem[w] = sq;
    __syncthreads();
    if (threadIdx.x == 0) atomicAdd(lacc, smem[0] + smem[1] + smem[2] + smem[3]);
}

__global__ void k_pred(const float* __restrict__ emb, const int* __restrict__ users,
                       const int* __restrict__ bundles, float* __restrict__ out) {
    int t = blockIdx.x * blockDim.x + threadIdx.x;
    if (t < NBATCH * KB) {
        int b = t / KB;
        int uidx = users[b];
        int bidx = bundles[t];
        const float4* ue = (const float4*)(emb + (size_t)uidx * EMB);
        const float4* be = (const float4*)(emb + (size_t)(NUU + NII + bidx) * EMB);
        float s = 0.0f;
#pragma unroll
        for (int j = 0; j < 8; ++j) {
            float4 a = ue[j], bb = be[j];
            s += a.x * bb.x + a.y * bb.y + a.z * bb.z + a.w * bb.w;
        }
        out[t] = s;
    }
}

__global__ void k_usb(const float* __restrict__ emb, const int* __restrict__ users,
                      const float* __restrict__ ubound, const float* __restrict__ lacc,
                      float* __restrict__ out) {
    int b = blockIdx.x * blockDim.x + threadIdx.x;
    if (b < NBATCH) {
        int uidx = users[b];
        float s = 0.0f;
#pragma unroll
        for (int d = 0; d < EMB; ++d) s += emb[uidx * EMB + d] * ubound[d];
        out[NBATCH * KB + b] = s;
    }
    if (b == 0) out[NBATCH * KB + NBATCH] = L2F * lacc[0];
}

extern "C" void kernel_launch(void* const* d_in, const int* in_sizes, int n_in,
                              void* d_out, int out_size, void* d_ws, size_t ws_size,
                              hipStream_t stream) {
    const float* ufeat  = (const float*)d_in[0];
    const float* ifeat  = (const float*)d_in[1];
    const float* bfeat  = (const float*)d_in[2];
    const float* ubound = (const float*)d_in[3];
    const int* rows     = (const int*)d_in[4];
    const int* cols     = (const int*)d_in[5];
    const int* users    = (const int*)d_in[6];
    const int* bundles  = (const int*)d_in[7];
    float* out = (float*)d_out;

    // Workspace layout (all 4-byte elements).
    // [memset region: dv, de, lacc]
    int*   dv    = (int*)d_ws;                 // NTOT
    int*   de    = dv + NTOT;                  // NTOT
    float* lacc  = (float*)(de + NTOT);        // 1
    int*   off_r = (int*)(lacc + 1);           // NTOT
    int*   cur_r = off_r + NTOT;               // NTOT
    int*   off_c = cur_r + NTOT;               // NTOT
    int*   cur_c = off_c + NTOT;               // NTOT
    int*   adj_r = cur_c + NTOT;               // NNZ_E
    int*   adj_c = adj_r + NNZ_E;              // NNZ_E
    float* dvi   = (float*)(adj_c + NNZ_E);    // NTOT
    float* dei   = dvi + NTOT;                 // NTOT
    float* u     = dei + NTOT;                 // NTOT*EMB
    float* emb   = u + (size_t)NTOT * EMB;     // NTOT*EMB

    hipMemsetAsync(d_ws, 0, (size_t)(2 * NTOT + 1) * sizeof(int), stream);

    k_deg <<<(NNZ_E + 255) / 256, 256, 0, stream>>>(rows, cols, dv, de);
    k_scan<<<1, SCAN_T, 0, stream>>>(dv, de, off_r, cur_r, off_c, cur_c, dvi, dei);
    k_fill<<<(NNZ_E + 255) / 256, 256, 0, stream>>>(rows, cols, cur_r, cur_c, adj_r, adj_c);
    k_g1  <<<(NTOT * 64 + 255) / 256, 256, 0, stream>>>(off_c, de, adj_c,
                                                        ufeat, ifeat, bfeat, dvi, dei, u);
    k_g2  <<<(NTOT * 64 + 255) / 256, 256, 0, stream>>>(off_r, dv, adj_r,
                                                        ufeat, ifeat, bfeat, dvi, u, emb, lacc);
    k_pred<<<(NBATCH * KB + 255) / 256, 256, 0, stream>>>(emb, users, bundles, out);
    k_usb <<<(NBATCH + 255) / 256, 256, 0, stream>>>(emb, users, ubound, lacc, out);
}

// Round 5
// 1015.363 us; speedup vs baseline: 1.0893x; 1.0893x over previous
//
#include <hip/hip_runtime.h>

#define NUU 8039
#define NII 32770
#define NBB 4771
#define NTOT (NUU + NII + NBB)   // 45580
#define EMB 32
#define NNZ_E 2000000
#define EPSF 1e-8f
#define L2F 1e-5f
#define NBATCH 2048
#define KB 100

#define NBUCK 45          // node buckets of 1024 (45*1024 = 46080 >= NTOT)
#define BCAP 49152        // per-bucket capacity; mean 44932, sigma ~210 -> +20 sigma
#define NSPB 128          // split blocks
#define EPB (NNZ_E / NSPB) // 15625 edges per split block (exact: 128*15625 = 2e6)
#define SC_S 5            // edge-stream splits per (bucket, dim-half)

__device__ __forceinline__ float get_x(const float* __restrict__ ufeat,
                                       const float* __restrict__ ifeat,
                                       const float* __restrict__ bfeat,
                                       int i, int d) {
    if (i < NUU) return ufeat[i * EMB + d];
    if (i < NUU + NII) return ifeat[(i - NUU) * EMB + d];
    return bfeat[(i - NUU - NII) * EMB + d];
}

// Coarse 45-way multisplit of the edge list, both directions in one pass.
// Per round: LDS count -> one global atomic per touched bucket -> short
// coalesced scatter runs. Payload: (local_node_10b << 16) | other_node_16b.
__global__ __launch_bounds__(1024) void k_split(
        const int* __restrict__ rows, const int* __restrict__ cols,
        int* __restrict__ bcur_c, int* __restrict__ bcur_r,
        unsigned* __restrict__ bucket_c, unsigned* __restrict__ bucket_r) {
    __shared__ int lcnt_c[NBUCK], lcnt_r[NBUCK], base_c[NBUCK], base_r[NBUCK];
    int t = threadIdx.x;
    int lo = blockIdx.x * EPB, hi = lo + EPB;
    for (int e0 = lo; e0 < hi; e0 += 1024) {
        if (t < NBUCK) { lcnt_c[t] = 0; lcnt_r[t] = 0; }
        __syncthreads();
        int e = e0 + t;
        int r = 0, c = 0, bc = 0, br = 0, sc = 0, sr = 0;
        bool valid = (e < hi);
        if (valid) {
            r = rows[e]; c = cols[e];
            bc = c >> 10; br = r >> 10;
            sc = atomicAdd(&lcnt_c[bc], 1);
            sr = atomicAdd(&lcnt_r[br], 1);
        }
        __syncthreads();
        if (t < NBUCK) {
            if (lcnt_c[t] > 0) base_c[t] = atomicAdd(&bcur_c[t], lcnt_c[t]);
            if (lcnt_r[t] > 0) base_r[t] = atomicAdd(&bcur_r[t], lcnt_r[t]);
        }
        __syncthreads();
        if (valid) {
            bucket_c[(size_t)bc * BCAP + base_c[bc] + sc] =
                ((unsigned)(c & 1023) << 16) | (unsigned)r;
            bucket_r[(size_t)br * BCAP + base_r[br] + sr] =
                ((unsigned)(r & 1023) << 16) | (unsigned)c;
        }
        __syncthreads();
    }
}

// Degrees from buckets: per-bucket LDS histogram, no global atomics.
// blocks [0,45) -> dei from bucket_c; blocks [45,90) -> dvi from bucket_r.
__global__ __launch_bounds__(1024) void k_bdeg(
        const unsigned* __restrict__ bucket_c, const unsigned* __restrict__ bucket_r,
        const int* __restrict__ bcur_c, const int* __restrict__ bcur_r,
        float* __restrict__ dei, float* __restrict__ dvi) {
    __shared__ int h[1024];
    int isC = (blockIdx.x < NBUCK) ? 1 : 0;
    int b = isC ? blockIdx.x : blockIdx.x - NBUCK;
    const unsigned* bk = (isC ? bucket_c : bucket_r) + (size_t)b * BCAP;
    int cnt = (isC ? bcur_c : bcur_r)[b];
    h[threadIdx.x] = 0;
    __syncthreads();
    for (int k = threadIdx.x; k < cnt; k += 1024)
        atomicAdd(&h[bk[k] >> 16], 1);
    __syncthreads();
    int node = b * 1024 + threadIdx.x;
    if (node < NTOT) {
        float val = 1.0f / (sqrtf((float)h[threadIdx.x]) + EPSF);
        if (isC) dei[node] = val; else dvi[node] = val;
    }
}

// u[c][:] += x[r][:]*dvi[r] accumulated in a 1024x16 LDS tile (dim-half dh),
// flushed with coalesced global atomics, dei folded in at flush.
__global__ __launch_bounds__(1024) void k_scat_u(
        const unsigned* __restrict__ bucket_c, const int* __restrict__ bcur_c,
        const float* __restrict__ ufeat, const float* __restrict__ ifeat,
        const float* __restrict__ bfeat,
        const float* __restrict__ dvi, const float* __restrict__ dei,
        float* __restrict__ u) {
    __shared__ float tile[1024 * 16];
    int bid = blockIdx.x;                  // 45 * 2 * SC_S
    int b = bid / (2 * SC_S);
    int rem = bid % (2 * SC_S);
    int dh = rem / SC_S, s = rem % SC_S;
    int cnt = bcur_c[b];
    for (int i = threadIdx.x; i < 1024 * 16; i += 1024) tile[i] = 0.0f;
    __syncthreads();
    int lo = (int)((long long)cnt * s / SC_S);
    int hi = (int)((long long)cnt * (s + 1) / SC_S);
    int lane = threadIdx.x & 15, eh = threadIdx.x >> 4;   // 64 edge slots
    const unsigned* bk = bucket_c + (size_t)b * BCAP;
    int dbase = dh * 16 + lane;
    int k = lo + eh;
    unsigned pk = (k < hi) ? bk[k] : 0u;
    while (k < hi) {
        int kn = k + 64;
        unsigned pn = (kn < hi) ? bk[kn] : 0u;   // prefetch next edge
        int r = (int)(pk & 0xFFFFu);
        int cl = (int)(pk >> 16);
        float val = get_x(ufeat, ifeat, bfeat, r, dbase) * dvi[r];
        atomicAdd(&tile[cl * 16 + lane], val);
        pk = pn; k = kn;
    }
    __syncthreads();
#pragma unroll
    for (int j = 0; j < 16; ++j) {
        int idx = threadIdx.x + j * 1024;
        int node = b * 1024 + (idx >> 4);
        if (node < NTOT)
            atomicAdd(&u[(size_t)node * EMB + dh * 16 + (idx & 15)],
                      tile[idx] * dei[node]);
    }
}

// v[r][:] += u[c][:] accumulated likewise; dvi/3 folded in at flush.
__global__ __launch_bounds__(1024) void k_scat_v(
        const unsigned* __restrict__ bucket_r, const int* __restrict__ bcur_r,
        const float* __restrict__ u, const float* __restrict__ dvi,
        float* __restrict__ v) {
    __shared__ float tile[1024 * 16];
    int bid = blockIdx.x;
    int b = bid / (2 * SC_S);
    int rem = bid % (2 * SC_S);
    int dh = rem / SC_S, s = rem % SC_S;
    int cnt = bcur_r[b];
    for (int i = threadIdx.x; i < 1024 * 16; i += 1024) tile[i] = 0.0f;
    __syncthreads();
    int lo = (int)((long long)cnt * s / SC_S);
    int hi = (int)((long long)cnt * (s + 1) / SC_S);
    int lane = threadIdx.x & 15, eh = threadIdx.x >> 4;
    const unsigned* bk = bucket_r + (size_t)b * BCAP;
    int dbase = dh * 16 + lane;
    int k = lo + eh;
    unsigned pk = (k < hi) ? bk[k] : 0u;
    while (k < hi) {
        int kn = k + 64;
        unsigned pn = (kn < hi) ? bk[kn] : 0u;
        int c = (int)(pk & 0xFFFFu);
        int rl = (int)(pk >> 16);
        float val = u[(size_t)c * EMB + dbase];
        atomicAdd(&tile[rl * 16 + lane], val);
        pk = pn; k = kn;
    }
    __syncthreads();
#pragma unroll
    for (int j = 0; j < 16; ++j) {
        int idx = threadIdx.x + j * 1024;
        int node = b * 1024 + (idx >> 4);
        if (node < NTOT)
            atomicAdd(&v[(size_t)node * EMB + dh * 16 + (idx & 15)],
                      tile[idx] * (dvi[node] * (1.0f / 3.0f)));
    }
}

// emb = x/2 + v (v already scaled by dvi/3), in place over v; fused loss.
__global__ void k_emb(const float* __restrict__ ufeat, const float* __restrict__ ifeat,
                      const float* __restrict__ bfeat,
                      float* __restrict__ v, float* __restrict__ lacc) {
    int tid = blockIdx.x * blockDim.x + threadIdx.x;
    float sq = 0.0f;
    if (tid < NTOT * EMB) {
        int i = tid >> 5, d = tid & 31;
        float e = 0.5f * get_x(ufeat, ifeat, bfeat, i, d) + v[tid];
        v[tid] = e;
        sq = e * e;
    }
#pragma unroll
    for (int off = 32; off > 0; off >>= 1) sq += __shfl_down(sq, off, 64);
    __shared__ float smem[4];
    int lane = threadIdx.x & 63, w = threadIdx.x >> 6;
    if (lane == 0) smem[w] = sq;
    __syncthreads();
    if (threadIdx.x == 0) atomicAdd(lacc, smem[0] + smem[1] + smem[2] + smem[3]);
}

__global__ void k_pred(const float* __restrict__ emb, const int* __restrict__ users,
                       const int* __restrict__ bundles, float* __restrict__ out) {
    int t = blockIdx.x * blockDim.x + threadIdx.x;
    if (t < NBATCH * KB) {
        int b = t / KB;
        int uidx = users[b];
        int bidx = bundles[t];
        const float4* ue = (const float4*)(emb + (size_t)uidx * EMB);
        const float4* be = (const float4*)(emb + (size_t)(NUU + NII + bidx) * EMB);
        float s = 0.0f;
#pragma unroll
        for (int j = 0; j < 8; ++j) {
            float4 a = ue[j], bb = be[j];
            s += a.x * bb.x + a.y * bb.y + a.z * bb.z + a.w * bb.w;
        }
        out[t] = s;
    }
}

__global__ void k_usb(const float* __restrict__ emb, const int* __restrict__ users,
                      const float* __restrict__ ubound, const float* __restrict__ lacc,
                      float* __restrict__ out) {
    int b = blockIdx.x * blockDim.x + threadIdx.x;
    if (b < NBATCH) {
        int uidx = users[b];
        float s = 0.0f;
#pragma unroll
        for (int d = 0; d < EMB; ++d) s += emb[uidx * EMB + d] * ubound[d];
        out[NBATCH * KB + b] = s;
    }
    if (b == 0) out[NBATCH * KB + NBATCH] = L2F * lacc[0];
}

extern "C" void kernel_launch(void* const* d_in, const int* in_sizes, int n_in,
                              void* d_out, int out_size, void* d_ws, size_t ws_size,
                              hipStream_t stream) {
    const float* ufeat  = (const float*)d_in[0];
    const float* ifeat  = (const float*)d_in[1];
    const float* bfeat  = (const float*)d_in[2];
    const float* ubound = (const float*)d_in[3];
    const int* rows     = (const int*)d_in[4];
    const int* cols     = (const int*)d_in[5];
    const int* users    = (const int*)d_in[6];
    const int* bundles  = (const int*)d_in[7];
    float* out = (float*)d_out;

    // Workspace layout (ints):
    // [0]        bcur_c[45]
    // [45]       bcur_r[45]
    // [90]       lacc (float)
    // [91..127]  pad
    // [128]      u       [NTOT*EMB]
    // then       dvi[NTOT], dei[NTOT]
    // then       bucket_r[45*BCAP], bucket_c[45*BCAP]  (v overlays bucket_c)
    int* ws = (int*)d_ws;
    int*   bcur_c = ws;
    int*   bcur_r = ws + NBUCK;
    float* lacc   = (float*)(ws + 2 * NBUCK);
    float* u      = (float*)(ws + 128);
    float* dvi    = u + (size_t)NTOT * EMB;
    float* dei    = dvi + NTOT;
    unsigned* bucket_r = (unsigned*)(dei + NTOT);
    unsigned* bucket_c = bucket_r + (size_t)NBUCK * BCAP;
    float* v = (float*)bucket_c;   // overlay: bucket_c dead after k_scat_u

    // zero: bcur_c, bcur_r, lacc, pad, u  (contiguous front region)
    hipMemsetAsync(d_ws, 0, (size_t)(128 + NTOT * EMB) * sizeof(int), stream);

    k_split<<<NSPB, 1024, 0, stream>>>(rows, cols, bcur_c, bcur_r, bucket_c, bucket_r);
    k_bdeg <<<2 * NBUCK, 1024, 0, stream>>>(bucket_c, bucket_r, bcur_c, bcur_r, dei, dvi);
    k_scat_u<<<NBUCK * 2 * SC_S, 1024, 0, stream>>>(bucket_c, bcur_c,
                                                    ufeat, ifeat, bfeat, dvi, dei, u);
    // bucket_c is dead now; zero v (its overlay) before accumulating into it.
    hipMemsetAsync((void*)v, 0, (size_t)NTOT * EMB * sizeof(float), stream);
    k_scat_v<<<NBUCK * 2 * SC_S, 1024, 0, stream>>>(bucket_r, bcur_r, u, dvi, v);
    k_emb  <<<(NTOT * EMB + 255) / 256, 256, 0, stream>>>(ufeat, ifeat, bfeat, v, lacc);
    k_pred <<<(NBATCH * KB + 255) / 256, 256, 0, stream>>>(v, users, bundles, out);
    k_usb  <<<(NBATCH + 255) / 256, 256, 0, stream>>>(v, users, ubound, lacc, out);
}

// Round 10
// 997.283 us; speedup vs baseline: 1.1090x; 1.0181x over previous
//
#include <hip/hip_runtime.h>

#define NUU 8039
#define NII 32770
#define NBB 4771
#define NTOT (NUU + NII + NBB)   // 45580
#define EMB 32
#define NNZ_E 2000000
#define EPSF 1e-8f
#define L2F 1e-5f
#define NBATCH 2048
#define KB 100

#define NBUCK 90          // node buckets of 512 (90*512 = 46080 >= NTOT)
#define BCAP 24576        // per-bucket capacity; mean 22466, sigma ~149 -> +14 sigma
#define NSPB 128          // split blocks
#define EPB (NNZ_E / NSPB) // 15625 edges per split block
#define SC_S 5            // edge-stream splits per bucket

__device__ __forceinline__ float get_x(const float* __restrict__ ufeat,
                                       const float* __restrict__ ifeat,
                                       const float* __restrict__ bfeat,
                                       int i, int d) {
    if (i < NUU) return ufeat[i * EMB + d];
    if (i < NUU + NII) return ifeat[(i - NUU) * EMB + d];
    return bfeat[(i - NUU - NII) * EMB + d];
}

// Coarse 90-way multisplit of the edge list, both directions in one pass.
// Payload: (local_node_9b << 16) | other_node_16b.
__global__ __launch_bounds__(1024) void k_split(
        const int* __restrict__ rows, const int* __restrict__ cols,
        int* __restrict__ bcur_c, int* __restrict__ bcur_r,
        unsigned* __restrict__ bucket_c, unsigned* __restrict__ bucket_r) {
    __shared__ int lcnt_c[NBUCK], lcnt_r[NBUCK], base_c[NBUCK], base_r[NBUCK];
    int t = threadIdx.x;
    int lo = blockIdx.x * EPB, hi = lo + EPB;
    for (int e0 = lo; e0 < hi; e0 += 1024) {
        if (t < NBUCK) { lcnt_c[t] = 0; lcnt_r[t] = 0; }
        __syncthreads();
        int e = e0 + t;
        int r = 0, c = 0, bc = 0, br = 0, sc = 0, sr = 0;
        bool valid = (e < hi);
        if (valid) {
            r = rows[e]; c = cols[e];
            bc = c >> 9; br = r >> 9;
            sc = atomicAdd(&lcnt_c[bc], 1);
            sr = atomicAdd(&lcnt_r[br], 1);
        }
        __syncthreads();
        if (t < NBUCK) {
            if (lcnt_c[t] > 0) base_c[t] = atomicAdd(&bcur_c[t], lcnt_c[t]);
            if (lcnt_r[t] > 0) base_r[t] = atomicAdd(&bcur_r[t], lcnt_r[t]);
        }
        __syncthreads();
        if (valid) {
            bucket_c[(size_t)bc * BCAP + base_c[bc] + sc] =
                ((unsigned)(c & 511) << 16) | (unsigned)r;
            bucket_r[(size_t)br * BCAP + base_r[br] + sr] =
                ((unsigned)(r & 511) << 16) | (unsigned)c;
        }
        __syncthreads();
    }
}

// Degrees from buckets: per-bucket LDS histogram, no global atomics.
// blocks [0,90) -> dei from bucket_c; blocks [90,180) -> dvi from bucket_r.
__global__ __launch_bounds__(1024) void k_bdeg(
        const unsigned* __restrict__ bucket_c, const unsigned* __restrict__ bucket_r,
        const int* __restrict__ bcur_c, const int* __restrict__ bcur_r,
        float* __restrict__ dei, float* __restrict__ dvi) {
    __shared__ int h[512];
    int isC = (blockIdx.x < NBUCK) ? 1 : 0;
    int b = isC ? blockIdx.x : blockIdx.x - NBUCK;
    const unsigned* bk = (isC ? bucket_c : bucket_r) + (size_t)b * BCAP;
    int cnt = (isC ? bcur_c : bcur_r)[b];
    if (threadIdx.x < 512) h[threadIdx.x] = 0;
    __syncthreads();
    for (int k = threadIdx.x; k < cnt; k += 1024)
        atomicAdd(&h[bk[k] >> 16], 1);
    __syncthreads();
    int node = b * 512 + threadIdx.x;
    if (threadIdx.x < 512 && node < NTOT) {
        float val = 1.0f / (sqrtf((float)h[threadIdx.x]) + EPSF);
        if (isC) dei[node] = val; else dvi[node] = val;
    }
}

// xs[i][d] = x[i][d] * dvi[i]  (pre-scale: removes per-edge dvi load + branch)
__global__ void k_xs(const float* __restrict__ ufeat, const float* __restrict__ ifeat,
                     const float* __restrict__ bfeat, const float* __restrict__ dvi,
                     float* __restrict__ xs) {
    int tid = blockIdx.x * blockDim.x + threadIdx.x;
    if (tid < NTOT * EMB) {
        int i = tid >> 5, d = tid & 31;
        xs[tid] = get_x(ufeat, ifeat, bfeat, i, d) * dvi[i];
    }
}

// u[c][:] += xs[r][:] into a 512x32 LDS tile; unroll-8 gather for MLP;
// flush with coalesced global atomics, dei folded in at flush.
__global__ __launch_bounds__(1024) void k_scat_u(
        const unsigned* __restrict__ bucket_c, const int* __restrict__ bcur_c,
        const float* __restrict__ xs, const float* __restrict__ dei,
        float* __restrict__ u) {
    __shared__ float tile[512 * 32];
    int b = blockIdx.x / SC_S, s = blockIdx.x % SC_S;
    int cnt = bcur_c[b];
    for (int i = threadIdx.x; i < 512 * 32; i += 1024) tile[i] = 0.0f;
    __syncthreads();
    int lo = (int)((long long)cnt * s / SC_S);
    int hi = (int)((long long)cnt * (s + 1) / SC_S);
    int lane = threadIdx.x & 31, slot = threadIdx.x >> 5;   // 32 edge slots
    const unsigned* bk = bucket_c + (size_t)b * BCAP;
    int dbase = lane;
    int k = lo + slot;
    while (k + 7 * 32 < hi) {
        unsigned p0 = bk[k],         p1 = bk[k + 32],  p2 = bk[k + 64],  p3 = bk[k + 96];
        unsigned p4 = bk[k + 128],   p5 = bk[k + 160], p6 = bk[k + 192], p7 = bk[k + 224];
        float x0 = xs[(size_t)(p0 & 0xFFFFu) * EMB + dbase];
        float x1 = xs[(size_t)(p1 & 0xFFFFu) * EMB + dbase];
        float x2 = xs[(size_t)(p2 & 0xFFFFu) * EMB + dbase];
        float x3 = xs[(size_t)(p3 & 0xFFFFu) * EMB + dbase];
        float x4 = xs[(size_t)(p4 & 0xFFFFu) * EMB + dbase];
        float x5 = xs[(size_t)(p5 & 0xFFFFu) * EMB + dbase];
        float x6 = xs[(size_t)(p6 & 0xFFFFu) * EMB + dbase];
        float x7 = xs[(size_t)(p7 & 0xFFFFu) * EMB + dbase];
        atomicAdd(&tile[(p0 >> 16) * 32 + lane], x0);
        atomicAdd(&tile[(p1 >> 16) * 32 + lane], x1);
        atomicAdd(&tile[(p2 >> 16) * 32 + lane], x2);
        atomicAdd(&tile[(p3 >> 16) * 32 + lane], x3);
        atomicAdd(&tile[(p4 >> 16) * 32 + lane], x4);
        atomicAdd(&tile[(p5 >> 16) * 32 + lane], x5);
        atomicAdd(&tile[(p6 >> 16) * 32 + lane], x6);
        atomicAdd(&tile[(p7 >> 16) * 32 + lane], x7);
        k += 8 * 32;
    }
    while (k < hi) {
        unsigned p = bk[k];
        atomicAdd(&tile[(p >> 16) * 32 + lane], xs[(size_t)(p & 0xFFFFu) * EMB + lane]);
        k += 32;
    }
    __syncthreads();
#pragma unroll
    for (int j = 0; j < 16; ++j) {
        int idx = threadIdx.x + j * 1024;
        int node = b * 512 + (idx >> 5);
        if (node < NTOT)
            atomicAdd(&u[(size_t)node * EMB + (idx & 31)], tile[idx] * dei[node]);
    }
}

// v[r][:] += u[c][:] likewise; dvi/3 folded in at flush.
__global__ __launch_bounds__(1024) void k_scat_v(
        const unsigned* __restrict__ bucket_r, const int* __restrict__ bcur_r,
        const float* __restrict__ u, const float* __restrict__ dvi,
        float* __restrict__ v) {
    __shared__ float tile[512 * 32];
    int b = blockIdx.x / SC_S, s = blockIdx.x % SC_S;
    int cnt = bcur_r[b];
    for (int i = threadIdx.x; i < 512 * 32; i += 1024) tile[i] = 0.0f;
    __syncthreads();
    int lo = (int)((long long)cnt * s / SC_S);
    int hi = (int)((long long)cnt * (s + 1) / SC_S);
    int lane = threadIdx.x & 31, slot = threadIdx.x >> 5;
    const unsigned* bk = bucket_r + (size_t)b * BCAP;
    int k = lo + slot;
    while (k + 7 * 32 < hi) {
        unsigned p0 = bk[k],         p1 = bk[k + 32],  p2 = bk[k + 64],  p3 = bk[k + 96];
        unsigned p4 = bk[k + 128],   p5 = bk[k + 160], p6 = bk[k + 192], p7 = bk[k + 224];
        float x0 = u[(size_t)(p0 & 0xFFFFu) * EMB + lane];
        float x1 = u[(size_t)(p1 & 0xFFFFu) * EMB + lane];
        float x2 = u[(size_t)(p2 & 0xFFFFu) * EMB + lane];
        float x3 = u[(size_t)(p3 & 0xFFFFu) * EMB + lane];
        float x4 = u[(size_t)(p4 & 0xFFFFu) * EMB + lane];
        float x5 = u[(size_t)(p5 & 0xFFFFu) * EMB + lane];
        float x6 = u[(size_t)(p6 & 0xFFFFu) * EMB + lane];
        float x7 = u[(size_t)(p7 & 0xFFFFu) * EMB + lane];
        atomicAdd(&tile[(p0 >> 16) * 32 + lane], x0);
        atomicAdd(&tile[(p1 >> 16) * 32 + lane], x1);
        atomicAdd(&tile[(p2 >> 16) * 32 + lane], x2);
        atomicAdd(&tile[(p3 >> 16) * 32 + lane], x3);
        atomicAdd(&tile[(p4 >> 16) * 32 + lane], x4);
        atomicAdd(&tile[(p5 >> 16) * 32 + lane], x5);
        atomicAdd(&tile[(p6 >> 16) * 32 + lane], x6);
        atomicAdd(&tile[(p7 >> 16) * 32 + lane], x7);
        k += 8 * 32;
    }
    while (k < hi) {
        unsigned p = bk[k];
        atomicAdd(&tile[(p >> 16) * 32 + lane], u[(size_t)(p & 0xFFFFu) * EMB + lane]);
        k += 32;
    }
    __syncthreads();
#pragma unroll
    for (int j = 0; j < 16; ++j) {
        int idx = threadIdx.x + j * 1024;
        int node = b * 512 + (idx >> 5);
        if (node < NTOT)
            atomicAdd(&v[(size_t)node * EMB + (idx & 31)],
                      tile[idx] * (dvi[node] * (1.0f / 3.0f)));
    }
}

// emb = x/2 + v (v already scaled by dvi/3), in place over v; fused loss.
__global__ void k_emb(const float* __restrict__ ufeat, const float* __restrict__ ifeat,
                      const float* __restrict__ bfeat,
                      float* __restrict__ v, float* __restrict__ lacc) {
    int tid = blockIdx.x * blockDim.x + threadIdx.x;
    float sq = 0.0f;
    if (tid < NTOT * EMB) {
        int i = tid >> 5, d = tid & 31;
        float e = 0.5f * get_x(ufeat, ifeat, bfeat, i, d) + v[tid];
        v[tid] = e;
        sq = e * e;
    }
#pragma unroll
    for (int off = 32; off > 0; off >>= 1) sq += __shfl_down(sq, off, 64);
    __shared__ float smem[4];
    int lane = threadIdx.x & 63, w = threadIdx.x >> 6;
    if (lane == 0) smem[w] = sq;
    __syncthreads();
    if (threadIdx.x == 0) atomicAdd(lacc, smem[0] + smem[1] + smem[2] + smem[3]);
}

__global__ void k_pred(const float* __restrict__ emb, const int* __restrict__ users,
                       const int* __restrict__ bundles, float* __restrict__ out) {
    int t = blockIdx.x * blockDim.x + threadIdx.x;
    if (t < NBATCH * KB) {
        int b = t / KB;
        int uidx = users[b];
        int bidx = bundles[t];
        const float4* ue = (const float4*)(emb + (size_t)uidx * EMB);
        const float4* be = (const float4*)(emb + (size_t)(NUU + NII + bidx) * EMB);
        float s = 0.0f;
#pragma unroll
        for (int j = 0; j < 8; ++j) {
            float4 a = ue[j], bb = be[j];
            s += a.x * bb.x + a.y * bb.y + a.z * bb.z + a.w * bb.w;
        }
        out[t] = s;
    }
}

__global__ void k_usb(const float* __restrict__ emb, const int* __restrict__ users,
                      const float* __restrict__ ubound, const float* __restrict__ lacc,
                      float* __restrict__ out) {
    int b = blockIdx.x * blockDim.x + threadIdx.x;
    if (b < NBATCH) {
        int uidx = users[b];
        float s = 0.0f;
#pragma unroll
        for (int d = 0; d < EMB; ++d) s += emb[uidx * EMB + d] * ubound[d];
        out[NBATCH * KB + b] = s;
    }
    if (b == 0) out[NBATCH * KB + NBATCH] = L2F * lacc[0];
}

extern "C" void kernel_launch(void* const* d_in, const int* in_sizes, int n_in,
                              void* d_out, int out_size, void* d_ws, size_t ws_size,
                              hipStream_t stream) {
    const float* ufeat  = (const float*)d_in[0];
    const float* ifeat  = (const float*)d_in[1];
    const float* bfeat  = (const float*)d_in[2];
    const float* ubound = (const float*)d_in[3];
    const int* rows     = (const int*)d_in[4];
    const int* cols     = (const int*)d_in[5];
    const int* users    = (const int*)d_in[6];
    const int* bundles  = (const int*)d_in[7];
    float* out = (float*)d_out;

    // Workspace layout (4-byte elements):
    // [0]    bcur_c[90]
    // [90]   bcur_r[90]
    // [180]  lacc
    // pad to 256
    // [256]  u [NTOT*EMB]       (zeroed with front region)
    // then   dvi[NTOT], dei[NTOT]
    // then   xs [NTOT*EMB]
    // then   bucket_r[90*BCAP]
    // then   bucket_c[90*BCAP]  (v overlays bucket_c; dead after k_scat_u)
    int* ws = (int*)d_ws;
    int*   bcur_c = ws;
    int*   bcur_r = ws + NBUCK;
    float* lacc   = (float*)(ws + 2 * NBUCK);
    float* u      = (float*)(ws + 256);
    float* dvi    = u + (size_t)NTOT * EMB;
    float* dei    = dvi + NTOT;
    float* xs     = dei + NTOT;
    unsigned* bucket_r = (unsigned*)(xs + (size_t)NTOT * EMB);
    unsigned* bucket_c = bucket_r + (size_t)NBUCK * BCAP;
    float* v = (float*)bucket_c;   // overlay

    hipMemsetAsync(d_ws, 0, (size_t)(256 + NTOT * EMB) * sizeof(int), stream);

    k_split<<<NSPB, 1024, 0, stream>>>(rows, cols, bcur_c, bcur_r, bucket_c, bucket_r);
    k_bdeg <<<2 * NBUCK, 1024, 0, stream>>>(bucket_c, bucket_r, bcur_c, bcur_r, dei, dvi);
    k_xs   <<<(NTOT * EMB + 255) / 256, 256, 0, stream>>>(ufeat, ifeat, bfeat, dvi, xs);
    k_scat_u<<<NBUCK * SC_S, 1024, 0, stream>>>(bucket_c, bcur_c, xs, dei, u);
    // bucket_c dead; zero its overlay (v) before accumulating.
    hipMemsetAsync((void*)v, 0, (size_t)NTOT * EMB * sizeof(float), stream);
    k_scat_v<<<NBUCK * SC_S, 1024, 0, stream>>>(bucket_r, bcur_r, u, dvi, v);
    k_emb  <<<(NTOT * EMB + 255) / 256, 256, 0, stream>>>(ufeat, ifeat, bfeat, v, lacc);
    k_pred <<<(NBATCH * KB + 255) / 256, 256, 0, stream>>>(v, users, bundles, out);
    k_usb  <<<(NBATCH + 255) / 256, 256, 0, stream>>>(v, users, ubound, lacc, out);
}

// Round 15
// 382.835 us; speedup vs baseline: 2.8891x; 2.6050x over previous
//
#include <hip/hip_runtime.h>

#define NUU 8039
#define NII 32770
#define NBB 4771
#define NTOT (NUU + NII + NBB)   // 45580
#define EMB 32
#define NNZ_E 2000000
#define EPSF 1e-8f
#define L2F 1e-5f
#define NBATCH 2048
#define KB 100

#define NBUCK 90          // node buckets of 512 (90*512 = 46080 >= NTOT)
#define BCAP 24576        // per-bucket capacity; mean 22466, sigma ~149 -> +14 sigma
#define NSPB 128          // split blocks
#define EPB (NNZ_E / NSPB) // 15625 edges per split block

__device__ __forceinline__ float get_x(const float* __restrict__ ufeat,
                                       const float* __restrict__ ifeat,
                                       const float* __restrict__ bfeat,
                                       int i, int d) {
    if (i < NUU) return ufeat[i * EMB + d];
    if (i < NUU + NII) return ifeat[(i - NUU) * EMB + d];
    return bfeat[(i - NUU - NII) * EMB + d];
}

// Coarse 90-way multisplit of the edge list, both directions in one pass.
// Payload: (local_node_9b << 16) | other_node_16b.   [measured fast, round 10]
__global__ __launch_bounds__(1024) void k_split(
        const int* __restrict__ rows, const int* __restrict__ cols,
        int* __restrict__ bcur_c, int* __restrict__ bcur_r,
        unsigned* __restrict__ bucket_c, unsigned* __restrict__ bucket_r) {
    __shared__ int lcnt_c[NBUCK], lcnt_r[NBUCK], base_c[NBUCK], base_r[NBUCK];
    int t = threadIdx.x;
    int lo = blockIdx.x * EPB, hi = lo + EPB;
    for (int e0 = lo; e0 < hi; e0 += 1024) {
        if (t < NBUCK) { lcnt_c[t] = 0; lcnt_r[t] = 0; }
        __syncthreads();
        int e = e0 + t;
        int r = 0, c = 0, bc = 0, br = 0, sc = 0, sr = 0;
        bool valid = (e < hi);
        if (valid) {
            r = rows[e]; c = cols[e];
            bc = c >> 9; br = r >> 9;
            sc = atomicAdd(&lcnt_c[bc], 1);
            sr = atomicAdd(&lcnt_r[br], 1);
        }
        __syncthreads();
        if (t < NBUCK) {
            if (lcnt_c[t] > 0) base_c[t] = atomicAdd(&bcur_c[t], lcnt_c[t]);
            if (lcnt_r[t] > 0) base_r[t] = atomicAdd(&bcur_r[t], lcnt_r[t]);
        }
        __syncthreads();
        if (valid) {
            bucket_c[(size_t)bc * BCAP + base_c[bc] + sc] =
                ((unsigned)(c & 511) << 16) | (unsigned)r;
            bucket_r[(size_t)br * BCAP + base_r[br] + sr] =
                ((unsigned)(r & 511) << 16) | (unsigned)c;
        }
        __syncthreads();
    }
}

// Per-bucket CSR build: LDS histogram -> LDS 512-wide scan -> LDS-cursor fill.
// No global atomics; adj writes confined to this bucket's 48KB region (L2).
// blocks [0,90): c-direction (adj_c, off_c, deg_c, dei)
// blocks [90,180): r-direction (adj_r, off_r, deg_r, dvi)
__global__ __launch_bounds__(1024) void k_csr(
        const unsigned* __restrict__ bucket_c, const unsigned* __restrict__ bucket_r,
        const int* __restrict__ bcur_c, const int* __restrict__ bcur_r,
        unsigned short* __restrict__ adj_c, unsigned short* __restrict__ adj_r,
        int* __restrict__ off_c, int* __restrict__ deg_c,
        int* __restrict__ off_r, int* __restrict__ deg_r,
        float* __restrict__ dei, float* __restrict__ dvi) {
    __shared__ int h[512], soff[512], cur[512];
    int isC = (blockIdx.x < NBUCK) ? 1 : 0;
    int b = isC ? blockIdx.x : blockIdx.x - NBUCK;
    const unsigned* bk = (isC ? bucket_c : bucket_r) + (size_t)b * BCAP;
    unsigned short* adj = (isC ? adj_c : adj_r) + (size_t)b * BCAP;
    int cnt = (isC ? bcur_c : bcur_r)[b];
    int t = threadIdx.x;

    if (t < 512) h[t] = 0;
    __syncthreads();
    for (int k = t; k < cnt; k += 1024) atomicAdd(&h[bk[k] >> 16], 1);
    __syncthreads();
    if (t < 512) soff[t] = h[t];
    __syncthreads();
    for (int off = 1; off < 512; off <<= 1) {
        int v = 0;
        if (t < 512 && t >= off) v = soff[t - off];
        __syncthreads();
        if (t < 512) soff[t] += v;
        __syncthreads();
    }
    if (t < 512) {
        int base = soff[t] - h[t];        // exclusive prefix
        cur[t] = base;
        int node = b * 512 + t;
        if (node < NTOT) {
            float val = 1.0f / (sqrtf((float)h[t]) + EPSF);
            int o = b * BCAP + base;
            if (isC) { off_c[node] = o; deg_c[node] = h[t]; dei[node] = val; }
            else     { off_r[node] = o; deg_r[node] = h[t]; dvi[node] = val; }
        }
    }
    __syncthreads();
    for (int k = t; k < cnt; k += 1024) {
        unsigned e = bk[k];
        int pos = atomicAdd(&cur[e >> 16], 1);
        adj[pos] = (unsigned short)(e & 0xFFFFu);
    }
}

// xs[i][d] = x[i][d] * dvi[i]
__global__ void k_xs(const float* __restrict__ ufeat, const float* __restrict__ ifeat,
                     const float* __restrict__ bfeat, const float* __restrict__ dvi,
                     float* __restrict__ xs) {
    int tid = blockIdx.x * blockDim.x + threadIdx.x;
    if (tid < NTOT * EMB) {
        int i = tid >> 5, d = tid & 31;
        xs[tid] = get_x(ufeat, ifeat, bfeat, i, d) * dvi[i];
    }
}

// u[c][:] = dei[c] * sum_{r in adj_c[c]} xs[r][:]
// Wave per node: 32 lanes = dims, 2 halves split the list; unroll-4 MLP;
// register accumulation, coalesced direct store. No launch_bounds (VGPR room).
__global__ void k_g1(const int* __restrict__ off_c, const int* __restrict__ deg_c,
                     const unsigned short* __restrict__ adj_c,
                     const float* __restrict__ xs, const float* __restrict__ dei,
                     float* __restrict__ u) {
    int wid = (blockIdx.x * blockDim.x + threadIdx.x) >> 6;
    if (wid >= NTOT) return;
    int lane = threadIdx.x & 63, d = lane & 31, half = lane >> 5;
    int s = off_c[wid], e = s + deg_c[wid];
    float acc = 0.0f;
    int k = s + half;
    while (k + 6 < e) {
        int r0 = adj_c[k], r1 = adj_c[k + 2], r2 = adj_c[k + 4], r3 = adj_c[k + 6];
        float x0 = xs[(size_t)r0 * EMB + d];
        float x1 = xs[(size_t)r1 * EMB + d];
        float x2 = xs[(size_t)r2 * EMB + d];
        float x3 = xs[(size_t)r3 * EMB + d];
        acc += x0 + x1 + x2 + x3;
        k += 8;
    }
    for (; k < e; k += 2) acc += xs[(size_t)adj_c[k] * EMB + d];
    acc += __shfl_xor(acc, 32, 64);
    if (half == 0) u[(size_t)wid * EMB + d] = acc * dei[wid];
}

// emb[r][:] = x[r][:]/2 + dvi[r]/3 * sum_{c in adj_r[r]} u[c][:]; fused loss.
__global__ void k_g2(const int* __restrict__ off_r, const int* __restrict__ deg_r,
                     const unsigned short* __restrict__ adj_r,
                     const float* __restrict__ u, const float* __restrict__ dvi,
                     const float* __restrict__ ufeat, const float* __restrict__ ifeat,
                     const float* __restrict__ bfeat,
                     float* __restrict__ emb, float* __restrict__ lacc) {
    int wid = (blockIdx.x * blockDim.x + threadIdx.x) >> 6;
    int lane = threadIdx.x & 63;
    float sq = 0.0f;
    if (wid < NTOT) {
        int d = lane & 31, half = lane >> 5;
        int s = off_r[wid], e = s + deg_r[wid];
        float acc = 0.0f;
        int k = s + half;
        while (k + 6 < e) {
            int c0 = adj_r[k], c1 = adj_r[k + 2], c2 = adj_r[k + 4], c3 = adj_r[k + 6];
            float x0 = u[(size_t)c0 * EMB + d];
            float x1 = u[(size_t)c1 * EMB + d];
            float x2 = u[(size_t)c2 * EMB + d];
            float x3 = u[(size_t)c3 * EMB + d];
            acc += x0 + x1 + x2 + x3;
            k += 8;
        }
        for (; k < e; k += 2) acc += u[(size_t)adj_r[k] * EMB + d];
        acc += __shfl_xor(acc, 32, 64);
        if (half == 0) {
            float ev = 0.5f * get_x(ufeat, ifeat, bfeat, wid, d)
                     + (dvi[wid] * (1.0f / 3.0f)) * acc;
            emb[(size_t)wid * EMB + d] = ev;
            sq = ev * ev;
        }
    }
#pragma unroll
    for (int o = 32; o > 0; o >>= 1) sq += __shfl_down(sq, o, 64);
    __shared__ float sm[4];
    int w = threadIdx.x >> 6;
    if ((threadIdx.x & 63) == 0) sm[w] = sq;
    __syncthreads();
    if (threadIdx.x == 0) atomicAdd(lacc, sm[0] + sm[1] + sm[2] + sm[3]);
}

__global__ void k_pred(const float* __restrict__ emb, const int* __restrict__ users,
                       const int* __restrict__ bundles, float* __restrict__ out) {
    int t = blockIdx.x * blockDim.x + threadIdx.x;
    if (t < NBATCH * KB) {
        int b = t / KB;
        int uidx = users[b];
        int bidx = bundles[t];
        const float4* ue = (const float4*)(emb + (size_t)uidx * EMB);
        const float4* be = (const float4*)(emb + (size_t)(NUU + NII + bidx) * EMB);
        float s = 0.0f;
#pragma unroll
        for (int j = 0; j < 8; ++j) {
            float4 a = ue[j], bb = be[j];
            s += a.x * bb.x + a.y * bb.y + a.z * bb.z + a.w * bb.w;
        }
        out[t] = s;
    }
}

__global__ void k_usb(const float* __restrict__ emb, const int* __restrict__ users,
                      const float* __restrict__ ubound, const float* __restrict__ lacc,
                      float* __restrict__ out) {
    int b = blockIdx.x * blockDim.x + threadIdx.x;
    if (b < NBATCH) {
        int uidx = users[b];
        float s = 0.0f;
#pragma unroll
        for (int d = 0; d < EMB; ++d) s += emb[uidx * EMB + d] * ubound[d];
        out[NBATCH * KB + b] = s;
    }
    if (b == 0) out[NBATCH * KB + NBATCH] = L2F * lacc[0];
}

extern "C" void kernel_launch(void* const* d_in, const int* in_sizes, int n_in,
                              void* d_out, int out_size, void* d_ws, size_t ws_size,
                              hipStream_t stream) {
    const float* ufeat  = (const float*)d_in[0];
    const float* ifeat  = (const float*)d_in[1];
    const float* bfeat  = (const float*)d_in[2];
    const float* ubound = (const float*)d_in[3];
    const int* rows     = (const int*)d_in[4];
    const int* cols     = (const int*)d_in[5];
    const int* users    = (const int*)d_in[6];
    const int* bundles  = (const int*)d_in[7];
    float* out = (float*)d_out;

    // Workspace (4-byte units):
    // [0..89] bcur_c  [90..179] bcur_r  [180] lacc  pad->256   (memset region)
    // off_c[NTOT] deg_c[NTOT] off_r[NTOT] deg_r[NTOT]
    // dvi[NTOT] dei[NTOT]
    // u [NTOT*EMB]
    // xs[NTOT*EMB]              (emb overlays xs; xs dead after k_g1)
    // bucket_c[90*BCAP] u32
    // bucket_r[90*BCAP] u32
    // adj_c[90*BCAP] u16  (BCAP/2 ints)
    // adj_r[90*BCAP] u16
    int* ws = (int*)d_ws;
    int*   bcur_c = ws;
    int*   bcur_r = ws + NBUCK;
    float* lacc   = (float*)(ws + 2 * NBUCK);
    int*   off_c  = ws + 256;
    int*   deg_c  = off_c + NTOT;
    int*   off_r  = deg_c + NTOT;
    int*   deg_r  = off_r + NTOT;
    float* dvi    = (float*)(deg_r + NTOT);
    float* dei    = dvi + NTOT;
    float* u      = dei + NTOT;
    float* xs     = u + (size_t)NTOT * EMB;
    unsigned* bucket_c = (unsigned*)(xs + (size_t)NTOT * EMB);
    unsigned* bucket_r = bucket_c + (size_t)NBUCK * BCAP;
    unsigned short* adj_c = (unsigned short*)(bucket_r + (size_t)NBUCK * BCAP);
    unsigned short* adj_r = adj_c + (size_t)NBUCK * BCAP;
    float* emb = xs;   // overlay: xs dead after k_g1

    hipMemsetAsync(d_ws, 0, 256 * sizeof(int), stream);

    k_split<<<NSPB, 1024, 0, stream>>>(rows, cols, bcur_c, bcur_r, bucket_c, bucket_r);
    k_csr  <<<2 * NBUCK, 1024, 0, stream>>>(bucket_c, bucket_r, bcur_c, bcur_r,
                                            adj_c, adj_r, off_c, deg_c, off_r, deg_r,
                                            dei, dvi);
    k_xs   <<<(NTOT * EMB + 255) / 256, 256, 0, stream>>>(ufeat, ifeat, bfeat, dvi, xs);
    k_g1   <<<(NTOT * 64 + 255) / 256, 256, 0, stream>>>(off_c, deg_c, adj_c, xs, dei, u);
    k_g2   <<<(NTOT * 64 + 255) / 256, 256, 0, stream>>>(off_r, deg_r, adj_r, u, dvi,
                                                         ufeat, ifeat, bfeat, emb, lacc);
    k_pred <<<(NBATCH * KB + 255) / 256, 256, 0, stream>>>(emb, users, bundles, out);
    k_usb  <<<(NBATCH + 255) / 256, 256, 0, stream>>>(emb, users, ubound, lacc, out);
}

// Round 17
// 376.637 us; speedup vs baseline: 2.9366x; 1.0165x over previous
//
#include <hip/hip_runtime.h>

#define NUU 8039
#define NII 32770
#define NBB 4771
#define NTOT (NUU + NII + NBB)   // 45580
#define EMB 32
#define NNZ_E 2000000
#define EPSF 1e-8f
#define L2F 1e-5f
#define NBATCH 2048
#define KB 100

#define NBUCK 90          // node buckets of 512 (90*512 = 46080 >= NTOT)
#define BCAP 24576        // per-bucket capacity; mean 22466, sigma ~149 -> +14 sigma
#define NSPB 128          // split blocks
#define EPB (NNZ_E / NSPB) // 15625 edges per split block

__device__ __forceinline__ float get_x(const float* __restrict__ ufeat,
                                       const float* __restrict__ ifeat,
                                       const float* __restrict__ bfeat,
                                       int i, int d) {
    if (i < NUU) return ufeat[i * EMB + d];
    if (i < NUU + NII) return ifeat[(i - NUU) * EMB + d];
    return bfeat[(i - NUU - NII) * EMB + d];
}

// Coarse 90-way multisplit of the edge list, both directions in one pass.
// Payload: (local_node_9b << 16) | other_node_16b.   [measured fast, round 10]
__global__ __launch_bounds__(1024) void k_split(
        const int* __restrict__ rows, const int* __restrict__ cols,
        int* __restrict__ bcur_c, int* __restrict__ bcur_r,
        unsigned* __restrict__ bucket_c, unsigned* __restrict__ bucket_r) {
    __shared__ int lcnt_c[NBUCK], lcnt_r[NBUCK], base_c[NBUCK], base_r[NBUCK];
    int t = threadIdx.x;
    int lo = blockIdx.x * EPB, hi = lo + EPB;
    for (int e0 = lo; e0 < hi; e0 += 1024) {
        if (t < NBUCK) { lcnt_c[t] = 0; lcnt_r[t] = 0; }
        __syncthreads();
        int e = e0 + t;
        int r = 0, c = 0, bc = 0, br = 0, sc = 0, sr = 0;
        bool valid = (e < hi);
        if (valid) {
            r = rows[e]; c = cols[e];
            bc = c >> 9; br = r >> 9;
            sc = atomicAdd(&lcnt_c[bc], 1);
            sr = atomicAdd(&lcnt_r[br], 1);
        }
        __syncthreads();
        if (t < NBUCK) {
            if (lcnt_c[t] > 0) base_c[t] = atomicAdd(&bcur_c[t], lcnt_c[t]);
            if (lcnt_r[t] > 0) base_r[t] = atomicAdd(&bcur_r[t], lcnt_r[t]);
        }
        __syncthreads();
        if (valid) {
            bucket_c[(size_t)bc * BCAP + base_c[bc] + sc] =
                ((unsigned)(c & 511) << 16) | (unsigned)r;
            bucket_r[(size_t)br * BCAP + base_r[br] + sr] =
                ((unsigned)(r & 511) << 16) | (unsigned)c;
        }
        __syncthreads();
    }
}

// Per-bucket CSR build: LDS histogram -> LDS 512-wide scan -> LDS-cursor fill.
__global__ __launch_bounds__(1024) void k_csr(
        const unsigned* __restrict__ bucket_c, const unsigned* __restrict__ bucket_r,
        const int* __restrict__ bcur_c, const int* __restrict__ bcur_r,
        unsigned short* __restrict__ adj_c, unsigned short* __restrict__ adj_r,
        int* __restrict__ off_c, int* __restrict__ deg_c,
        int* __restrict__ off_r, int* __restrict__ deg_r,
        float* __restrict__ dei, float* __restrict__ dvi) {
    __shared__ int h[512], soff[512], cur[512];
    int isC = (blockIdx.x < NBUCK) ? 1 : 0;
    int b = isC ? blockIdx.x : blockIdx.x - NBUCK;
    const unsigned* bk = (isC ? bucket_c : bucket_r) + (size_t)b * BCAP;
    unsigned short* adj = (isC ? adj_c : adj_r) + (size_t)b * BCAP;
    int cnt = (isC ? bcur_c : bcur_r)[b];
    int t = threadIdx.x;

    if (t < 512) h[t] = 0;
    __syncthreads();
    for (int k = t; k < cnt; k += 1024) atomicAdd(&h[bk[k] >> 16], 1);
    __syncthreads();
    if (t < 512) soff[t] = h[t];
    __syncthreads();
    for (int off = 1; off < 512; off <<= 1) {
        int v = 0;
        if (t < 512 && t >= off) v = soff[t - off];
        __syncthreads();
        if (t < 512) soff[t] += v;
        __syncthreads();
    }
    if (t < 512) {
        int base = soff[t] - h[t];        // exclusive prefix
        cur[t] = base;
        int node = b * 512 + t;
        if (node < NTOT) {
            float val = 1.0f / (sqrtf((float)h[t]) + EPSF);
            int o = b * BCAP + base;
            if (isC) { off_c[node] = o; deg_c[node] = h[t]; dei[node] = val; }
            else     { off_r[node] = o; deg_r[node] = h[t]; dvi[node] = val; }
        }
    }
    __syncthreads();
    for (int k = t; k < cnt; k += 1024) {
        unsigned e = bk[k];
        int pos = atomicAdd(&cur[e >> 16], 1);
        adj[pos] = (unsigned short)(e & 0xFFFFu);
    }
}

// xs[i][d] = x[i][d] * dvi[i]
__global__ void k_xs(const float* __restrict__ ufeat, const float* __restrict__ ifeat,
                     const float* __restrict__ bfeat, const float* __restrict__ dvi,
                     float* __restrict__ xs) {
    int tid = blockIdx.x * blockDim.x + threadIdx.x;
    if (tid < NTOT * EMB) {
        int i = tid >> 5, d = tid & 31;
        xs[tid] = get_x(ufeat, ifeat, bfeat, i, d) * dvi[i];
    }
}

// u[c][:] = dei[c] * sum_{r in adj_c[c]} xs[r][:]
// Wave per node: 4 edge-groups x 16 lanes x float2 -> 4 lines per load instr,
// 16 lines in flight with unroll-4 (4x the MLP of the 2x32 layout).
__global__ void k_g1(const int* __restrict__ off_c, const int* __restrict__ deg_c,
                     const unsigned short* __restrict__ adj_c,
                     const float2* __restrict__ xs2, const float* __restrict__ dei,
                     float2* __restrict__ u2) {
    int wid = (blockIdx.x * blockDim.x + threadIdx.x) >> 6;
    if (wid >= NTOT) return;
    int lane = threadIdx.x & 63;
    int dl = lane & 15, g = lane >> 4;      // dim-pair, edge-group
    int s = off_c[wid], e = s + deg_c[wid];
    float ax = 0.0f, ay = 0.0f;
    int k = s + g;
    while (k + 12 < e) {
        int r0 = adj_c[k], r1 = adj_c[k + 4], r2 = adj_c[k + 8], r3 = adj_c[k + 12];
        float2 v0 = xs2[(size_t)r0 * 16 + dl];
        float2 v1 = xs2[(size_t)r1 * 16 + dl];
        float2 v2 = xs2[(size_t)r2 * 16 + dl];
        float2 v3 = xs2[(size_t)r3 * 16 + dl];
        ax += v0.x + v1.x + v2.x + v3.x;
        ay += v0.y + v1.y + v2.y + v3.y;
        k += 16;
    }
    for (; k < e; k += 4) {
        float2 v = xs2[(size_t)adj_c[k] * 16 + dl];
        ax += v.x; ay += v.y;
    }
    ax += __shfl_xor(ax, 16, 64); ay += __shfl_xor(ay, 16, 64);
    ax += __shfl_xor(ax, 32, 64); ay += __shfl_xor(ay, 32, 64);
    if (g == 0) {
        float sc = dei[wid];
        u2[(size_t)wid * 16 + dl] = make_float2(ax * sc, ay * sc);
    }
}

// emb[r][:] = x[r][:]/2 + dvi[r]/3 * sum_{c in adj_r[r]} u[c][:]; fused loss.
__global__ void k_g2(const int* __restrict__ off_r, const int* __restrict__ deg_r,
                     const unsigned short* __restrict__ adj_r,
                     const float2* __restrict__ u2, const float* __restrict__ dvi,
                     const float* __restrict__ ufeat, const float* __restrict__ ifeat,
                     const float* __restrict__ bfeat,
                     float2* __restrict__ emb2, float* __restrict__ lacc) {
    int wid = (blockIdx.x * blockDim.x + threadIdx.x) >> 6;
    int lane = threadIdx.x & 63;
    float sq = 0.0f;
    if (wid < NTOT) {
        int dl = lane & 15, g = lane >> 4;
        int s = off_r[wid], e = s + deg_r[wid];
        float ax = 0.0f, ay = 0.0f;
        int k = s + g;
        while (k + 12 < e) {
            int c0 = adj_r[k], c1 = adj_r[k + 4], c2 = adj_r[k + 8], c3 = adj_r[k + 12];
            float2 v0 = u2[(size_t)c0 * 16 + dl];
            float2 v1 = u2[(size_t)c1 * 16 + dl];
            float2 v2 = u2[(size_t)c2 * 16 + dl];
            float2 v3 = u2[(size_t)c3 * 16 + dl];
            ax += v0.x + v1.x + v2.x + v3.x;
            ay += v0.y + v1.y + v2.y + v3.y;
            k += 16;
        }
        for (; k < e; k += 4) {
            float2 v = u2[(size_t)adj_r[k] * 16 + dl];
            ax += v.x; ay += v.y;
        }
        ax += __shfl_xor(ax, 16, 64); ay += __shfl_xor(ay, 16, 64);
        ax += __shfl_xor(ax, 32, 64); ay += __shfl_xor(ay, 32, 64);
        if (g == 0) {
            float sc = dvi[wid] * (1.0f / 3.0f);
            float ex = 0.5f * get_x(ufeat, ifeat, bfeat, wid, 2 * dl)     + sc * ax;
            float ey = 0.5f * get_x(ufeat, ifeat, bfeat, wid, 2 * dl + 1) + sc * ay;
            emb2[(size_t)wid * 16 + dl] = make_float2(ex, ey);
            sq = ex * ex + ey * ey;
        }
    }
#pragma unroll
    for (int o = 32; o > 0; o >>= 1) sq += __shfl_down(sq, o, 64);
    __shared__ float sm[4];
    int w = threadIdx.x >> 6;
    if ((threadIdx.x & 63) == 0) sm[w] = sq;
    __syncthreads();
    if (threadIdx.x == 0) atomicAdd(lacc, sm[0] + sm[1] + sm[2] + sm[3]);
}

__global__ void k_pred(const float* __restrict__ emb, const int* __restrict__ users,
                       const int* __restrict__ bundles, float* __restrict__ out) {
    int t = blockIdx.x * blockDim.x + threadIdx.x;
    if (t < NBATCH * KB) {
        int b = t / KB;
        int uidx = users[b];
        int bidx = bundles[t];
        const float4* ue = (const float4*)(emb + (size_t)uidx * EMB);
        const float4* be = (const float4*)(emb + (size_t)(NUU + NII + bidx) * EMB);
        float s = 0.0f;
#pragma unroll
        for (int j = 0; j < 8; ++j) {
            float4 a = ue[j], bb = be[j];
            s += a.x * bb.x + a.y * bb.y + a.z * bb.z + a.w * bb.w;
        }
        out[t] = s;
    }
}

__global__ void k_usb(const float* __restrict__ emb, const int* __restrict__ users,
                      const float* __restrict__ ubound, const float* __restrict__ lacc,
                      float* __restrict__ out) {
    int b = blockIdx.x * blockDim.x + threadIdx.x;
    if (b < NBATCH) {
        int uidx = users[b];
        float s = 0.0f;
#pragma unroll
        for (int d = 0; d < EMB; ++d) s += emb[uidx * EMB + d] * ubound[d];
        out[NBATCH * KB + b] = s;
    }
    if (b == 0) out[NBATCH * KB + NBATCH] = L2F * lacc[0];
}

extern "C" void kernel_launch(void* const* d_in, const int* in_sizes, int n_in,
                              void* d_out, int out_size, void* d_ws, size_t ws_size,
                              hipStream_t stream) {
    const float* ufeat  = (const float*)d_in[0];
    const float* ifeat  = (const float*)d_in[1];
    const float* bfeat  = (const float*)d_in[2];
    const float* ubound = (const float*)d_in[3];
    const int* rows     = (const int*)d_in[4];
    const int* cols     = (const int*)d_in[5];
    const int* users    = (const int*)d_in[6];
    const int* bundles  = (const int*)d_in[7];
    float* out = (float*)d_out;

    // Workspace (4-byte units):
    // [0..89] bcur_c  [90..179] bcur_r  [180] lacc  pad->256   (memset region)
    // off_c[NTOT] deg_c[NTOT] off_r[NTOT] deg_r[NTOT]
    // dvi[NTOT] dei[NTOT]
    // u [NTOT*EMB]
    // xs[NTOT*EMB]              (emb overlays xs; xs dead after k_g1)
    // bucket_c[90*BCAP] u32
    // bucket_r[90*BCAP] u32
    // adj_c[90*BCAP] u16
    // adj_r[90*BCAP] u16
    int* ws = (int*)d_ws;
    int*   bcur_c = ws;
    int*   bcur_r = ws + NBUCK;
    float* lacc   = (float*)(ws + 2 * NBUCK);
    int*   off_c  = ws + 256;
    int*   deg_c  = off_c + NTOT;
    int*   off_r  = deg_c + NTOT;
    int*   deg_r  = off_r + NTOT;
    float* dvi    = (float*)(deg_r + NTOT);
    float* dei    = dvi + NTOT;
    float* u      = dei + NTOT;
    float* xs     = u + (size_t)NTOT * EMB;
    unsigned* bucket_c = (unsigned*)(xs + (size_t)NTOT * EMB);
    unsigned* bucket_r = bucket_c + (size_t)NBUCK * BCAP;
    unsigned short* adj_c = (unsigned short*)(bucket_r + (size_t)NBUCK * BCAP);
    unsigned short* adj_r = adj_c + (size_t)NBUCK * BCAP;
    float* emb = xs;   // overlay: xs dead after k_g1

    hipMemsetAsync(d_ws, 0, 256 * sizeof(int), stream);

    k_split<<<NSPB, 1024, 0, stream>>>(rows, cols, bcur_c, bcur_r, bucket_c, bucket_r);
    k_csr  <<<2 * NBUCK, 1024, 0, stream>>>(bucket_c, bucket_r, bcur_c, bcur_r,
                                            adj_c, adj_r, off_c, deg_c, off_r, deg_r,
                                            dei, dvi);
    k_xs   <<<(NTOT * EMB + 255) / 256, 256, 0, stream>>>(ufeat, ifeat, bfeat, dvi, xs);
    k_g1   <<<(NTOT * 64 + 255) / 256, 256, 0, stream>>>(off_c, deg_c, adj_c,
                                                         (const float2*)xs, dei,
                                                         (float2*)u);
    k_g2   <<<(NTOT * 64 + 255) / 256, 256, 0, stream>>>(off_r, deg_r, adj_r,
                                                         (const float2*)u, dvi,
                                                         ufeat, ifeat, bfeat,
                                                         (float2*)emb, lacc);
    k_pred <<<(NBATCH * KB + 255) / 256, 256, 0, stream>>>(emb, users, bundles, out);
    k_usb  <<<(NBATCH + 255) / 256, 256, 0, stream>>>(emb, users, ubound, lacc, out);
}

// Round 18
// 361.716 us; speedup vs baseline: 3.0577x; 1.0413x over previous
//
#include <hip/hip_runtime.h>
#include <hip/hip_fp16.h>

#define NUU 8039
#define NII 32770
#define NBB 4771
#define NTOT (NUU + NII + NBB)   // 45580
#define EMB 32
#define NNZ_E 2000000
#define EPSF 1e-8f
#define L2F 1e-5f
#define NBATCH 2048
#define KB 100

#define NBUCK 90          // node buckets of 512 (90*512 = 46080 >= NTOT)
#define BCAP 24576        // per-bucket capacity; mean 22466, sigma ~149 -> +14 sigma
#define NSPB 128          // split blocks
#define EPB (NNZ_E / NSPB) // 15625 edges per split block

__device__ __forceinline__ float get_x(const float* __restrict__ ufeat,
                                       const float* __restrict__ ifeat,
                                       const float* __restrict__ bfeat,
                                       int i, int d) {
    if (i < NUU) return ufeat[i * EMB + d];
    if (i < NUU + NII) return ifeat[(i - NUU) * EMB + d];
    return bfeat[(i - NUU - NII) * EMB + d];
}

// Coarse 90-way multisplit of the edge list, both directions in one pass.
__global__ __launch_bounds__(1024) void k_split(
        const int* __restrict__ rows, const int* __restrict__ cols,
        int* __restrict__ bcur_c, int* __restrict__ bcur_r,
        unsigned* __restrict__ bucket_c, unsigned* __restrict__ bucket_r) {
    __shared__ int lcnt_c[NBUCK], lcnt_r[NBUCK], base_c[NBUCK], base_r[NBUCK];
    int t = threadIdx.x;
    int lo = blockIdx.x * EPB, hi = lo + EPB;
    for (int e0 = lo; e0 < hi; e0 += 1024) {
        if (t < NBUCK) { lcnt_c[t] = 0; lcnt_r[t] = 0; }
        __syncthreads();
        int e = e0 + t;
        int r = 0, c = 0, bc = 0, br = 0, sc = 0, sr = 0;
        bool valid = (e < hi);
        if (valid) {
            r = rows[e]; c = cols[e];
            bc = c >> 9; br = r >> 9;
            sc = atomicAdd(&lcnt_c[bc], 1);
            sr = atomicAdd(&lcnt_r[br], 1);
        }
        __syncthreads();
        if (t < NBUCK) {
            if (lcnt_c[t] > 0) base_c[t] = atomicAdd(&bcur_c[t], lcnt_c[t]);
            if (lcnt_r[t] > 0) base_r[t] = atomicAdd(&bcur_r[t], lcnt_r[t]);
        }
        __syncthreads();
        if (valid) {
            bucket_c[(size_t)bc * BCAP + base_c[bc] + sc] =
                ((unsigned)(c & 511) << 16) | (unsigned)r;
            bucket_r[(size_t)br * BCAP + base_r[br] + sr] =
                ((unsigned)(r & 511) << 16) | (unsigned)c;
        }
        __syncthreads();
    }
}

// Per-bucket CSR build: LDS histogram -> LDS 512-wide scan -> LDS-cursor fill.
__global__ __launch_bounds__(1024) void k_csr(
        const unsigned* __restrict__ bucket_c, const unsigned* __restrict__ bucket_r,
        const int* __restrict__ bcur_c, const int* __restrict__ bcur_r,
        unsigned short* __restrict__ adj_c, unsigned short* __restrict__ adj_r,
        int* __restrict__ off_c, int* __restrict__ deg_c,
        int* __restrict__ off_r, int* __restrict__ deg_r,
        float* __restrict__ dei, float* __restrict__ dvi) {
    __shared__ int h[512], soff[512], cur[512];
    int isC = (blockIdx.x < NBUCK) ? 1 : 0;
    int b = isC ? blockIdx.x : blockIdx.x - NBUCK;
    const unsigned* bk = (isC ? bucket_c : bucket_r) + (size_t)b * BCAP;
    unsigned short* adj = (isC ? adj_c : adj_r) + (size_t)b * BCAP;
    int cnt = (isC ? bcur_c : bcur_r)[b];
    int t = threadIdx.x;

    if (t < 512) h[t] = 0;
    __syncthreads();
    for (int k = t; k < cnt; k += 1024) atomicAdd(&h[bk[k] >> 16], 1);
    __syncthreads();
    if (t < 512) soff[t] = h[t];
    __syncthreads();
    for (int off = 1; off < 512; off <<= 1) {
        int v = 0;
        if (t < 512 && t >= off) v = soff[t - off];
        __syncthreads();
        if (t < 512) soff[t] += v;
        __syncthreads();
    }
    if (t < 512) {
        int base = soff[t] - h[t];        // exclusive prefix
        cur[t] = base;
        int node = b * 512 + t;
        if (node < NTOT) {
            float val = 1.0f / (sqrtf((float)h[t]) + EPSF);
            int o = b * BCAP + base;
            if (isC) { off_c[node] = o; deg_c[node] = h[t]; dei[node] = val; }
            else     { off_r[node] = o; deg_r[node] = h[t]; dvi[node] = val; }
        }
    }
    __syncthreads();
    for (int k = t; k < cnt; k += 1024) {
        unsigned e = bk[k];
        int pos = atomicAdd(&cur[e >> 16], 1);
        adj[pos] = (unsigned short)(e & 0xFFFFu);
    }
}

// xs_h[i][p] = half2(x[i][2p], x[i][2p+1]) * dvi[i]   (fp16 row = 64 B = 1 line)
__global__ void k_xs(const float* __restrict__ ufeat, const float* __restrict__ ifeat,
                     const float* __restrict__ bfeat, const float* __restrict__ dvi,
                     __half2* __restrict__ xs2) {
    int tid = blockIdx.x * blockDim.x + threadIdx.x;
    if (tid < NTOT * 16) {
        int i = tid >> 4, p = tid & 15;
        float sc = dvi[i];
        float a = get_x(ufeat, ifeat, bfeat, i, 2 * p) * sc;
        float b = get_x(ufeat, ifeat, bfeat, i, 2 * p + 1) * sc;
        xs2[tid] = __floats2half2_rn(a, b);
    }
}

// u[c][:] = dei[c] * sum_{r in adj_c[c]} xs[r][:]   (fp16 gather, f32 accum)
// Wave per node: 4 edge-groups x 16 lanes x half2; each row = 1 cache line.
__global__ void k_g1(const int* __restrict__ off_c, const int* __restrict__ deg_c,
                     const unsigned short* __restrict__ adj_c,
                     const __half2* __restrict__ xs2, const float* __restrict__ dei,
                     __half2* __restrict__ u2) {
    int wid = (blockIdx.x * blockDim.x + threadIdx.x) >> 6;
    if (wid >= NTOT) return;
    int lane = threadIdx.x & 63;
    int dl = lane & 15, g = lane >> 4;      // dim-pair, edge-group
    int s = off_c[wid], e = s + deg_c[wid];
    float ax = 0.0f, ay = 0.0f;
    int k = s + g;
    while (k + 12 < e) {
        int r0 = adj_c[k], r1 = adj_c[k + 4], r2 = adj_c[k + 8], r3 = adj_c[k + 12];
        float2 v0 = __half22float2(xs2[(size_t)r0 * 16 + dl]);
        float2 v1 = __half22float2(xs2[(size_t)r1 * 16 + dl]);
        float2 v2 = __half22float2(xs2[(size_t)r2 * 16 + dl]);
        float2 v3 = __half22float2(xs2[(size_t)r3 * 16 + dl]);
        ax += v0.x + v1.x + v2.x + v3.x;
        ay += v0.y + v1.y + v2.y + v3.y;
        k += 16;
    }
    for (; k < e; k += 4) {
        float2 v = __half22float2(xs2[(size_t)adj_c[k] * 16 + dl]);
        ax += v.x; ay += v.y;
    }
    ax += __shfl_xor(ax, 16, 64); ay += __shfl_xor(ay, 16, 64);
    ax += __shfl_xor(ax, 32, 64); ay += __shfl_xor(ay, 32, 64);
    if (g == 0) {
        float sc = dei[wid];
        u2[(size_t)wid * 16 + dl] = __floats2half2_rn(ax * sc, ay * sc);
    }
}

// emb[r][:] = x[r][:]/2 + dvi[r]/3 * sum_{c in adj_r[r]} u[c][:]; fused loss.
// x-term and emb stay f32 (exact); only the gathered u is fp16.
__global__ void k_g2(const int* __restrict__ off_r, const int* __restrict__ deg_r,
                     const unsigned short* __restrict__ adj_r,
                     const __half2* __restrict__ u2, const float* __restrict__ dvi,
                     const float* __restrict__ ufeat, const float* __restrict__ ifeat,
                     const float* __restrict__ bfeat,
                     float2* __restrict__ emb2, float* __restrict__ lacc) {
    int wid = (blockIdx.x * blockDim.x + threadIdx.x) >> 6;
    int lane = threadIdx.x & 63;
    float sq = 0.0f;
    if (wid < NTOT) {
        int dl = lane & 15, g = lane >> 4;
        int s = off_r[wid], e = s + deg_r[wid];
        float ax = 0.0f, ay = 0.0f;
        int k = s + g;
        while (k + 12 < e) {
            int c0 = adj_r[k], c1 = adj_r[k + 4], c2 = adj_r[k + 8], c3 = adj_r[k + 12];
            float2 v0 = __half22float2(u2[(size_t)c0 * 16 + dl]);
            float2 v1 = __half22float2(u2[(size_t)c1 * 16 + dl]);
            float2 v2 = __half22float2(u2[(size_t)c2 * 16 + dl]);
            float2 v3 = __half22float2(u2[(size_t)c3 * 16 + dl]);
            ax += v0.x + v1.x + v2.x + v3.x;
            ay += v0.y + v1.y + v2.y + v3.y;
            k += 16;
        }
        for (; k < e; k += 4) {
            float2 v = __half22float2(u2[(size_t)adj_r[k] * 16 + dl]);
            ax += v.x; ay += v.y;
        }
        ax += __shfl_xor(ax, 16, 64); ay += __shfl_xor(ay, 16, 64);
        ax += __shfl_xor(ax, 32, 64); ay += __shfl_xor(ay, 32, 64);
        if (g == 0) {
            float sc = dvi[wid] * (1.0f / 3.0f);
            float ex = 0.5f * get_x(ufeat, ifeat, bfeat, wid, 2 * dl)     + sc * ax;
            float ey = 0.5f * get_x(ufeat, ifeat, bfeat, wid, 2 * dl + 1) + sc * ay;
            emb2[(size_t)wid * 16 + dl] = make_float2(ex, ey);
            sq = ex * ex + ey * ey;
        }
    }
#pragma unroll
    for (int o = 32; o > 0; o >>= 1) sq += __shfl_down(sq, o, 64);
    __shared__ float sm[4];
    int w = threadIdx.x >> 6;
    if ((threadIdx.x & 63) == 0) sm[w] = sq;
    __syncthreads();
    if (threadIdx.x == 0) atomicAdd(lacc, sm[0] + sm[1] + sm[2] + sm[3]);
}

__global__ void k_pred(const float* __restrict__ emb, const int* __restrict__ users,
                       const int* __restrict__ bundles, float* __restrict__ out) {
    int t = blockIdx.x * blockDim.x + threadIdx.x;
    if (t < NBATCH * KB) {
        int b = t / KB;
        int uidx = users[b];
        int bidx = bundles[t];
        const float4* ue = (const float4*)(emb + (size_t)uidx * EMB);
        const float4* be = (const float4*)(emb + (size_t)(NUU + NII + bidx) * EMB);
        float s = 0.0f;
#pragma unroll
        for (int j = 0; j < 8; ++j) {
            float4 a = ue[j], bb = be[j];
            s += a.x * bb.x + a.y * bb.y + a.z * bb.z + a.w * bb.w;
        }
        out[t] = s;
    }
}

__global__ void k_usb(const float* __restrict__ emb, const int* __restrict__ users,
                      const float* __restrict__ ubound, const float* __restrict__ lacc,
                      float* __restrict__ out) {
    int b = blockIdx.x * blockDim.x + threadIdx.x;
    if (b < NBATCH) {
        int uidx = users[b];
        float s = 0.0f;
#pragma unroll
        for (int d = 0; d < EMB; ++d) s += emb[uidx * EMB + d] * ubound[d];
        out[NBATCH * KB + b] = s;
    }
    if (b == 0) out[NBATCH * KB + NBATCH] = L2F * lacc[0];
}

extern "C" void kernel_launch(void* const* d_in, const int* in_sizes, int n_in,
                              void* d_out, int out_size, void* d_ws, size_t ws_size,
                              hipStream_t stream) {
    const float* ufeat  = (const float*)d_in[0];
    const float* ifeat  = (const float*)d_in[1];
    const float* bfeat  = (const float*)d_in[2];
    const float* ubound = (const float*)d_in[3];
    const int* rows     = (const int*)d_in[4];
    const int* cols     = (const int*)d_in[5];
    const int* users    = (const int*)d_in[6];
    const int* bundles  = (const int*)d_in[7];
    float* out = (float*)d_out;

    // Workspace (4-byte units):
    // [0..89] bcur_c  [90..179] bcur_r  [180] lacc  pad->256   (memset region)
    // off_c[NTOT] deg_c[NTOT] off_r[NTOT] deg_r[NTOT]
    // dvi[NTOT] dei[NTOT]
    // xs_h [NTOT*16] half2
    // u_h  [NTOT*16] half2
    // emb  [NTOT*EMB] f32
    // bucket_c[90*BCAP] u32, bucket_r[90*BCAP] u32
    // adj_c[90*BCAP] u16, adj_r[90*BCAP] u16
    int* ws = (int*)d_ws;
    int*   bcur_c = ws;
    int*   bcur_r = ws + NBUCK;
    float* lacc   = (float*)(ws + 2 * NBUCK);
    int*   off_c  = ws + 256;
    int*   deg_c  = off_c + NTOT;
    int*   off_r  = deg_c + NTOT;
    int*   deg_r  = off_r + NTOT;
    float* dvi    = (float*)(deg_r + NTOT);
    float* dei    = dvi + NTOT;
    __half2* xs_h = (__half2*)(dei + NTOT);          // NTOT*16 elems (4B each)
    __half2* u_h  = xs_h + (size_t)NTOT * 16;
    float* emb    = (float*)(u_h + (size_t)NTOT * 16);
    unsigned* bucket_c = (unsigned*)(emb + (size_t)NTOT * EMB);
    unsigned* bucket_r = bucket_c + (size_t)NBUCK * BCAP;
    unsigned short* adj_c = (unsigned short*)(bucket_r + (size_t)NBUCK * BCAP);
    unsigned short* adj_r = adj_c + (size_t)NBUCK * BCAP;

    hipMemsetAsync(d_ws, 0, 256 * sizeof(int), stream);

    k_split<<<NSPB, 1024, 0, stream>>>(rows, cols, bcur_c, bcur_r, bucket_c, bucket_r);
    k_csr  <<<2 * NBUCK, 1024, 0, stream>>>(bucket_c, bucket_r, bcur_c, bcur_r,
                                            adj_c, adj_r, off_c, deg_c, off_r, deg_r,
                                            dei, dvi);
    k_xs   <<<(NTOT * 16 + 255) / 256, 256, 0, stream>>>(ufeat, ifeat, bfeat, dvi, xs_h);
    k_g1   <<<(NTOT * 64 + 255) / 256, 256, 0, stream>>>(off_c, deg_c, adj_c,
                                                         xs_h, dei, u_h);
    k_g2   <<<(NTOT * 64 + 255) / 256, 256, 0, stream>>>(off_r, deg_r, adj_r,
                                                         u_h, dvi,
                                                         ufeat, ifeat, bfeat,
                                                         (float2*)emb, lacc);
    k_pred <<<(NBATCH * KB + 255) / 256, 256, 0, stream>>>(emb, users, bundles, out);
    k_usb  <<<(NBATCH + 255) / 256, 256, 0, stream>>>(emb, users, ubound, lacc, out);
}